// Round 4
// baseline (355.528 us; speedup 1.0000x reference)
//
#include <hip/hip_runtime.h>
#include <hip/hip_bf16.h>

using uint32   = unsigned int;
using ushort_t = unsigned short;
using short8   = __attribute__((ext_vector_type(8))) short;
using floatx16 = __attribute__((ext_vector_type(16))) float;

#define M_DIM 32
#define K_DIM 8192
#define N_DIM 28672
#define QROW  (N_DIM/8)     /* 3584 dwords per qweight row */

// f16-origin tensors are uploaded by the harness as FLOAT32 ("else float*").
// Only g_xr (ours) is bf16, feeding the MFMA A operand.
__device__ ushort_t g_xr[M_DIM * K_DIM];   // 512 KB, fully rewritten each call

__device__ __forceinline__ ushort_t f2bf(float f){
  return __builtin_bit_cast(ushort_t, __float2bfloat16(f)); // RNE
}

// ---------------- rotation: x f32 (32,8192) -> g_xr bf16 ----------------
// one 64-lane unit per (m, g): 128-elem group, 8 Givens rounds in fp32 LDS
__global__ __launch_bounds__(256) void rotate_kernel(
    const float* __restrict__ x, const float* __restrict__ theta,
    const int* __restrict__ pairs, const float* __restrict__ cs)
{
  __shared__ float xb[4][128];
  const int u    = threadIdx.x >> 6;
  const int lane = threadIdx.x & 63;
  const int id   = blockIdx.x * 4 + u;   // 0..2047 = m*64+g
  const int m    = id >> 6;
  const int g    = id & 63;
  const float* xp = x + m*K_DIM + g*128;
  xb[u][lane]    = xp[lane];
  xb[u][lane+64] = xp[lane+64];
  #pragma unroll 1
  for (int k = 0; k < 8; ++k){
    __syncthreads();
    const int i = pairs[k*128 + 2*lane];
    const int j = pairs[k*128 + 2*lane + 1];
    const float th = theta[k*(K_DIM/2) + g*64 + lane];
    const float c = cosf(th), s = sinf(th);
    const float xi = xb[u][i], xj = xb[u][j];
    // pairs within a round are disjoint: this lane owns {i,j}
    xb[u][i] = c*xi - s*xj;
    xb[u][j] = s*xi + c*xj;
  }
  __syncthreads();
  const int base = g*128;
  g_xr[m*K_DIM + base + lane]      = f2bf(xb[u][lane]    * cs[base+lane]);
  g_xr[m*K_DIM + base + lane + 64] = f2bf(xb[u][lane+64] * cs[base+lane+64]);
}

// ---------------- fused GEMM + reduce + bias -> f32 out ----------------
// One 32-wide n-tile per block. 8 waves k-split K/8=1024 each, one
// 32x32x16 mfma accumulator per wave, LDS reduction at the end.
__global__ __launch_bounds__(512) void gemm_kernel(
    const uint32* __restrict__ qw,
    const uint32* __restrict__ qz, const float* __restrict__ scales,
    const float* __restrict__ bias, float* __restrict__ out)
{
  __shared__ float red[8*1024];   // 32 KB: 8 waves x (32x32) fp32
  const int bid  = blockIdx.x;
  // XCD-local n-ranges: the 4 tiles sharing a 64B qweight line stay on one XCD
  const int tile = (bid & 7)*112 + (bid >> 3);   // 0..895, bijective
  const int n0   = tile * 32;
  const int w    = threadIdx.x >> 6;   // 0..7: k-split slice
  const int lane = threadIdx.x & 63;
  const int l31  = lane & 31;
  const int koct = lane >> 5;          // k-octet within mfma K=16
  const int n    = n0 + l31;
  const int col  = n >> 3;             // qweight dword column
  const int sh   = (n & 7) * 4;        // nibble shift

  floatx16 acc;
  #pragma unroll
  for (int i = 0; i < 16; ++i) acc[i] = 0.f;

  const int g0 = w * 8;                // 8 quant-groups (of 128 k) per wave
  #pragma unroll 1
  for (int gi = 0; gi < 8; ++gi){
    const int g  = g0 + gi;
    const uint32 zq = qz[g*QROW + col];
    const float s  = scales[g*N_DIM + n];
    const float zs = (float)((zq >> sh) & 15u) * s;
    const int kg = g*128;
    #pragma unroll 1
    for (int kk = 0; kk < 128; kk += 16){
      const int kb = kg + kk + koct*8;
      const short8 a = *(const short8*)(g_xr + l31*K_DIM + kb);
      const uint32* qp = qw + (size_t)kb*QROW + col;
      uint32 q[8];
      #pragma unroll
      for (int j = 0; j < 8; ++j) q[j] = qp[(size_t)j*QROW];
      short8 b;
      #pragma unroll
      for (int j = 0; j < 8; ++j){
        const float wv = fmaf((float)((q[j] >> sh) & 15u), s, -zs); // (nib-z)*s
        b[j] = (short)f2bf(wv);
      }
      acc = __builtin_amdgcn_mfma_f32_32x32x16_bf16(a, b, acc, 0, 0, 0);
    }
  }
  // C/D layout (HW-verified m74/m101): col=lane&31, row=(r&3)+8*(r>>2)+4*(lane>>5)
  #pragma unroll
  for (int r = 0; r < 16; ++r){
    const int row = (r & 3) + 8*(r >> 2) + 4*koct;
    red[w*1024 + row*32 + l31] = acc[r];
  }
  __syncthreads();
  // reduce 8 slabs + bias -> out; threads t and t+512 handle 1024 outputs
  for (int idx = threadIdx.x; idx < 1024; idx += 512){
    float sum = 0.f;
    #pragma unroll
    for (int ww = 0; ww < 8; ++ww) sum += red[ww*1024 + idx];
    const int row = idx >> 5;
    const int cc  = idx & 31;
    out[row*N_DIM + n0 + cc] = sum + bias[n0 + cc];
  }
}

extern "C" void kernel_launch(void* const* d_in, const int* in_sizes, int n_in,
                              void* d_out, int out_size, void* d_ws, size_t ws_size,
                              hipStream_t stream)
{
  const float*  x      = (const float*)d_in[0];
  const uint32* qw     = (const uint32*)d_in[1];
  const uint32* qz     = (const uint32*)d_in[2];
  const float*  scales = (const float*)d_in[3];
  const float*  bias   = (const float*)d_in[4];
  const float*  theta  = (const float*)d_in[5];
  const int*    pairs  = (const int*)d_in[6];
  const float*  cs     = (const float*)d_in[7];
  float* out = (float*)d_out;

  rotate_kernel<<<dim3((M_DIM*64)/4), dim3(256), 0, stream>>>(x, theta, pairs, cs);
  gemm_kernel<<<dim3(N_DIM/32), dim3(512), 0, stream>>>(qw, qz, scales, bias, out);
}

// Round 5
// 252.184 us; speedup vs baseline: 1.4098x; 1.4098x over previous
//
#include <hip/hip_runtime.h>
#include <hip/hip_bf16.h>

using uint32   = unsigned int;
using ushort_t = unsigned short;
using short8   = __attribute__((ext_vector_type(8))) short;
using uint4v   = __attribute__((ext_vector_type(4))) uint32;
using floatx16 = __attribute__((ext_vector_type(16))) float;

#define M_DIM 32
#define K_DIM 8192
#define N_DIM 28672
#define QROW  (N_DIM/8)   /* 3584 dwords per qweight k-row */
#define KSPLIT 8
#define BN    256         /* n per block (128 B of qweight per k-row) */
#define CH    128         /* k-rows per chunk == QGS (one quant group) */
#define NCH   8           /* chunks per block: 1024 k / 128 */

typedef __attribute__((address_space(3))) uint32 lds_u32;
typedef const __attribute__((address_space(1))) uint32 glb_u32;

__device__ ushort_t g_xr[M_DIM * K_DIM];   // rotated x, bf16 (512 KB)
__device__ float    g_S[64 * M_DIM];       // per-group row sums of bf16(xr)

__device__ __forceinline__ float bf2f(ushort_t u){
  unsigned int v = ((unsigned int)u) << 16;
  return __builtin_bit_cast(float, v);
}
__device__ __forceinline__ ushort_t f2bf(float f){
  return __builtin_bit_cast(ushort_t, __float2bfloat16(f)); // RNE
}

// ---------------- rotation + group sums -------------------------------
// one 64-lane unit per (m, g): 128-elem group, 8 Givens rounds in LDS.
// pairs/theta preloaded to registers so rounds are pure LDS+VALU.
__global__ __launch_bounds__(256) void rotate_kernel(
    const float* __restrict__ x, const float* __restrict__ theta,
    const int* __restrict__ pairs, const float* __restrict__ cs)
{
  __shared__ float xb[4][128];
  const int u    = threadIdx.x >> 6;
  const int lane = threadIdx.x & 63;
  const int id   = blockIdx.x * 4 + u;   // 0..2047 = m*64+g
  const int m    = id >> 6;
  const int g    = id & 63;
  const float* xp = x + m*K_DIM + g*128;
  // preload all rounds' indices/angles (per-lane registers)
  int   ip[8], jp[8];
  float cv[8], sv[8];
  #pragma unroll
  for (int k = 0; k < 8; ++k){
    ip[k] = pairs[k*128 + 2*lane];
    jp[k] = pairs[k*128 + 2*lane + 1];
    const float th = theta[k*(K_DIM/2) + g*64 + lane];
    cv[k] = cosf(th); sv[k] = sinf(th);
  }
  xb[u][lane]    = xp[lane];
  xb[u][lane+64] = xp[lane+64];
  #pragma unroll
  for (int k = 0; k < 8; ++k){
    __syncthreads();
    const float xi = xb[u][ip[k]], xj = xb[u][jp[k]];
    xb[u][ip[k]] = cv[k]*xi - sv[k]*xj;
    xb[u][jp[k]] = sv[k]*xi + cv[k]*xj;
  }
  __syncthreads();
  const int base = g*128;
  const ushort_t b0 = f2bf(xb[u][lane]    * cs[base+lane]);
  const ushort_t b1 = f2bf(xb[u][lane+64] * cs[base+lane+64]);
  g_xr[m*K_DIM + base + lane]      = b0;
  g_xr[m*K_DIM + base + lane + 64] = b1;
  // group sum of the bf16-rounded values (must match gemm's A exactly)
  float sum = bf2f(b0) + bf2f(b1);
  #pragma unroll
  for (int d = 32; d > 0; d >>= 1) sum += __shfl_xor(sum, d, 64);
  if (lane == 0) g_S[g*32 + m] = sum;
}

// ---------------- init: out = bias (fp32) ------------------------------
__global__ __launch_bounds__(256) void init_kernel(
    const float* __restrict__ bias, float* __restrict__ out)
{
  const int n = blockIdx.x*256 + threadIdx.x;
  out[(size_t)blockIdx.y*N_DIM + n] = bias[n];
}

// ---------------- GEMM: staged LDS + raw-nibble MFMA + group fix -------
// grid 896 = (N/256) x KSPLIT. 8 waves = 8 n-subtiles of 32; each wave
// does the block's full 1024-k slice. Double-buffered 16 KB chunks.
__global__ __launch_bounds__(512) void gemm_kernel(
    const uint32* __restrict__ qw, const uint32* __restrict__ qz,
    const float* __restrict__ scales, float* __restrict__ out)
{
  __shared__ uint32 sq[2][CH*32];   // 2 x 16 KB
  const int bid  = blockIdx.x;
  const int ks   = bid & 7;
  const int nb   = bid >> 3;
  const int w    = threadIdx.x >> 6;
  const int lane = threadIdx.x & 63;
  const int l31  = lane & 31;
  const int koct = lane >> 5;
  const int n0   = nb * BN;
  const int n    = n0 + w*32 + l31;
  const int col  = n >> 3;
  const uint32 sh = (uint32)((n & 7) * 4);
  const int dwi  = w*4 + (l31 >> 3);   // dword index in 32-dword row
  const int kbase0 = ks * 1024;

  float accT[16];
  #pragma unroll
  for (int r = 0; r < 16; ++r) accT[r] = 0.f;

  auto stage = [&](int c){
    uint32* lp0 = &sq[c & 1][0];
    #pragma unroll
    for (int i = 0; i < 2; ++i){
      const int rl = w*16 + i*8 + (lane >> 3);      // row within chunk
      const size_t kglob = (size_t)(kbase0 + c*CH + rl);
      const uint32* gp = qw + kglob*QROW + (n0 >> 3) + (lane & 7)*4;
      uint32* lp = lp0 + (size_t)(w*16 + i*8)*32 + (size_t)lane*4;
      __builtin_amdgcn_global_load_lds((glb_u32*)gp, (lds_u32*)lp, 16, 0, 0);
    }
  };

  stage(0);
  #pragma unroll 1
  for (int c = 0; c < NCH; ++c){
    __syncthreads();                    // chunk c staged (vmcnt drained)
    if (c + 1 < NCH) stage(c + 1);      // prefetch overlaps compute
    const int g = ks*NCH + c;
    const uint32 zq = qz[(size_t)g*QROW + col];
    const float  s  = scales[(size_t)g*N_DIM + n];
    const float  zz = (float)(128u + ((zq >> sh) & 15u));
    const uint32* sqc = &sq[c & 1][0];
    const ushort_t* arow = g_xr + (size_t)l31*K_DIM + kbase0 + c*CH + koct*8;

    floatx16 acc;
    #pragma unroll
    for (int r = 0; r < 16; ++r) acc[r] = 0.f;

    #pragma unroll
    for (int kk8 = 0; kk8 < 8; ++kk8){            // 8 MFMAs per chunk
      const short8 a = *(const short8*)(arow + kk8*16);
      const int qb = (kk8*16 + koct*8)*32 + dwi;
      const uint32 q0 = sqc[qb], q1 = sqc[qb+32], q2 = sqc[qb+64], q3 = sqc[qb+96];
      const uint32 q4 = sqc[qb+128], q5 = sqc[qb+160], q6 = sqc[qb+192], q7 = sqc[qb+224];
      uint4v bp;
      bp.x = (((q0 >> sh) & 15u) | (((q1 >> sh) & 15u) << 16)) | 0x43004300u;
      bp.y = (((q2 >> sh) & 15u) | (((q3 >> sh) & 15u) << 16)) | 0x43004300u;
      bp.z = (((q4 >> sh) & 15u) | (((q5 >> sh) & 15u) << 16)) | 0x43004300u;
      bp.w = (((q6 >> sh) & 15u) | (((q7 >> sh) & 15u) << 16)) | 0x43004300u;
      const short8 b = __builtin_bit_cast(short8, bp);
      acc = __builtin_amdgcn_mfma_f32_32x32x16_bf16(a, b, acc, 0, 0, 0);
    }
    // per-group correction: out += s * (acc - (128+z) * S_g[row])
    #pragma unroll
    for (int r = 0; r < 16; ++r){
      const int row = (r & 3) + 8*(r >> 2) + 4*koct;
      const float t = fmaf(-zz, g_S[g*32 + row], acc[r]);
      accT[r] = fmaf(s, t, accT[r]);
    }
  }
  // C/D layout (HW-verified m74/m101): col=lane&31, row=(r&3)+8*(r>>2)+4*koct
  #pragma unroll
  for (int r = 0; r < 16; ++r){
    const int row = (r & 3) + 8*(r >> 2) + 4*koct;
    atomicAdd(out + (size_t)row*N_DIM + n, accT[r]);
  }
}

extern "C" void kernel_launch(void* const* d_in, const int* in_sizes, int n_in,
                              void* d_out, int out_size, void* d_ws, size_t ws_size,
                              hipStream_t stream)
{
  const float*  x      = (const float*)d_in[0];
  const uint32* qw     = (const uint32*)d_in[1];
  const uint32* qz     = (const uint32*)d_in[2];
  const float*  scales = (const float*)d_in[3];
  const float*  bias   = (const float*)d_in[4];
  const float*  theta  = (const float*)d_in[5];
  const int*    pairs  = (const int*)d_in[6];
  const float*  cs     = (const float*)d_in[7];
  float* out = (float*)d_out;

  rotate_kernel<<<dim3((M_DIM*64)/4), dim3(256), 0, stream>>>(x, theta, pairs, cs);
  init_kernel<<<dim3(N_DIM/256, M_DIM), dim3(256), 0, stream>>>(bias, out);
  gemm_kernel<<<dim3((N_DIM/BN)*KSPLIT), dim3(512), 0, stream>>>(qw, qz, scales, out);
}

// Round 6
// 247.694 us; speedup vs baseline: 1.4353x; 1.0181x over previous
//
#include <hip/hip_runtime.h>
#include <hip/hip_bf16.h>

using uint32   = unsigned int;
using ushort_t = unsigned short;
using short8   = __attribute__((ext_vector_type(8))) short;
using uint4v   = __attribute__((ext_vector_type(4))) uint32;
using floatx16 = __attribute__((ext_vector_type(16))) float;

#define M_DIM 32
#define K_DIM 8192
#define N_DIM 28672
#define QROW  (N_DIM/8)   /* 3584 dwords per qweight k-row */
#define KSPLIT 8
#define BN    256
#define CH    128         /* k per chunk == QGS */
#define NCH   8           /* chunks per block */
#define TSTRIDE 132       /* T row stride in dwords (128 + 4 pad) */

typedef __attribute__((address_space(3))) uint32 lds_u32;
typedef const __attribute__((address_space(1))) uint32 glb_u32;

__device__ ushort_t g_xr2[M_DIM * K_DIM]; // rotated x, k-octet-major MFMA-A order
__device__ float    g_S[64 * M_DIM];      // per-group row sums of bf16(xr)

__device__ __forceinline__ float bf2f(ushort_t u){
  unsigned int v = ((unsigned int)u) << 16;
  return __builtin_bit_cast(float, v);
}
__device__ __forceinline__ ushort_t f2bf(float f){
  return __builtin_bit_cast(ushort_t, __float2bfloat16(f)); // RNE
}

// ---------------- rotation + group sums --------------------------------
// one 64-lane unit per (m, g). Output layout: element (m,k) ->
// g_xr2[((k>>3)*32 + m)*8 + (k&7)]  (contiguous per-chunk A slices).
__global__ __launch_bounds__(256) void rotate_kernel(
    const float* __restrict__ x, const float* __restrict__ theta,
    const int* __restrict__ pairs, const float* __restrict__ cs)
{
  __shared__ float xb[4][128];
  const int u    = threadIdx.x >> 6;
  const int lane = threadIdx.x & 63;
  const int id   = blockIdx.x * 4 + u;   // 0..2047 = m*64+g
  const int m    = id >> 6;
  const int g    = id & 63;
  const float* xp = x + m*K_DIM + g*128;
  int   ip[8], jp[8];
  float cv[8], sv[8];
  #pragma unroll
  for (int k = 0; k < 8; ++k){
    ip[k] = pairs[k*128 + 2*lane];
    jp[k] = pairs[k*128 + 2*lane + 1];
    const float th = theta[k*(K_DIM/2) + g*64 + lane];
    cv[k] = cosf(th); sv[k] = sinf(th);
  }
  xb[u][lane]    = xp[lane];
  xb[u][lane+64] = xp[lane+64];
  #pragma unroll
  for (int k = 0; k < 8; ++k){
    __syncthreads();
    const float xi = xb[u][ip[k]], xj = xb[u][jp[k]];
    xb[u][ip[k]] = cv[k]*xi - sv[k]*xj;
    xb[u][jp[k]] = sv[k]*xi + cv[k]*xj;
  }
  __syncthreads();
  const int base = g*128;
  const int k0 = base + lane, k1 = base + lane + 64;
  const ushort_t b0 = f2bf(xb[u][lane]    * cs[k0]);
  const ushort_t b1 = f2bf(xb[u][lane+64] * cs[k1]);
  g_xr2[(((size_t)(k0>>3))*32 + m)*8 + (k0&7)] = b0;
  g_xr2[(((size_t)(k1>>3))*32 + m)*8 + (k1&7)] = b1;
  float sum = bf2f(b0) + bf2f(b1);
  #pragma unroll
  for (int d = 32; d > 0; d >>= 1) sum += __shfl_xor(sum, d, 64);
  if (lane == 0) g_S[g*M_DIM + m] = sum;
}

// ------------- init2: out = bias - sum_g s*(128+z)*S_g -----------------
__global__ __launch_bounds__(256) void init2_kernel(
    const uint32* __restrict__ qz, const float* __restrict__ scales,
    const float* __restrict__ bias, float* __restrict__ out)
{
  const int n = blockIdx.x*256 + threadIdx.x;
  const uint32 sh = (uint32)((n & 7)*4);
  float acc[M_DIM];
  const float b = bias[n];
  #pragma unroll
  for (int m = 0; m < M_DIM; ++m) acc[m] = b;
  #pragma unroll 1
  for (int g = 0; g < 64; ++g){
    const float s  = scales[(size_t)g*N_DIM + n];
    const uint32 zq = qz[(size_t)g*QROW + (n>>3)];
    const float t  = s * (float)(128u + ((zq >> sh) & 15u));
    #pragma unroll
    for (int m = 0; m < M_DIM; ++m)
      acc[m] = fmaf(-t, g_S[g*M_DIM + m], acc[m]);
  }
  #pragma unroll
  for (int m = 0; m < M_DIM; ++m) out[(size_t)m*N_DIM + n] = acc[m];
}

// ---------------- GEMM: A lds-dbuf, B vgpr->transposed-LDS -------------
__global__ __launch_bounds__(512, 4) void gemm_kernel(
    const uint32* __restrict__ qw, const float* __restrict__ scales,
    float* __restrict__ out)
{
  __shared__ uint32   T[32*TSTRIDE];        // 16.9 KB transposed B chunk
  __shared__ ushort_t A[2][CH*32];          // 2 x 8 KB A chunk (octet-major)
  const int bid  = blockIdx.x;
  const int ks   = bid & 7;
  const int nb   = bid >> 3;
  const int tid  = threadIdx.x;
  const int w    = tid >> 6;
  const int lane = tid & 63;
  const int l31  = lane & 31;
  const int koct = lane >> 5;
  const int n0   = nb * BN;
  const int n    = n0 + w*32 + l31;
  const uint32 sh = (uint32)((l31 & 7)*4);
  const int col  = w*4 + (l31 >> 3);        // T column for this lane
  const int k0   = ks * (NCH*CH);           // 1024*ks

  // B global-load mapping (per thread, 2 x dwordx4 per chunk)
  const int brow = tid >> 3;                // 0..63
  const int bcq  = tid & 7;                 // 0..7
  const uint32* bbase = qw + (size_t)(k0 + brow)*QROW + (n0>>3) + bcq*4;
  // A chunk c slice: g_xr2 + (k0 + c*CH)*32 elements, contiguous 8 KB
  const ushort_t* abase = g_xr2 + (size_t)k0*32;

  float accT[16];
  #pragma unroll
  for (int r = 0; r < 16; ++r) accT[r] = 0.f;

  uint4v bv[2][2];

  auto stageA = [&](int c){
    const ushort_t* gp = abase + (size_t)c*CH*32 + w*512 + lane*8;
    ushort_t* lp = &A[c & 1][0] + w*512;    // wave-uniform base; HW adds lane*16
    __builtin_amdgcn_global_load_lds((glb_u32*)gp, (lds_u32*)lp, 16, 0, 0);
  };

  // prelude: chunk 0
  bv[0][0] = *(const uint4v*)(bbase);
  bv[0][1] = *(const uint4v*)(bbase + (size_t)64*QROW);
  stageA(0);
  #pragma unroll
  for (int j = 0; j < 4; ++j){
    T[(bcq*4 + j)*TSTRIDE + brow]      = bv[0][0][j];
    T[(bcq*4 + j)*TSTRIDE + brow + 64] = bv[0][1][j];
  }

  #pragma unroll
  for (int c = 0; c < NCH; ++c){
    __syncthreads();                        // T(c) + A(c) visible
    const int cb = c & 1, nx = cb ^ 1;
    if (c + 1 < NCH){                       // prefetch after barrier: drain is compute-covered
      const uint32* bb = bbase + (size_t)(c+1)*CH*QROW;
      bv[nx][0] = *(const uint4v*)(bb);
      bv[nx][1] = *(const uint4v*)(bb + (size_t)64*QROW);
      stageA(c+1);
    }
    const float s = scales[(size_t)(ks*NCH + c)*N_DIM + n];
    floatx16 acc;
    #pragma unroll
    for (int r = 0; r < 16; ++r) acc[r] = 0.f;
    #pragma unroll
    for (int kk = 0; kk < 8; ++kk){
      const short8 a = *(const short8*)(&A[cb][((kk*2 + koct)*32 + l31)*8]);
      const uint32* tp = &T[col*TSTRIDE + kk*16 + koct*8];
      const uint4v p0 = *(const uint4v*)(tp);
      const uint4v p1 = *(const uint4v*)(tp + 4);
      uint4v bp;
      bp.x = ((p0.x >> sh) & 15u) | (((p0.y >> sh) & 15u) << 16) | 0x43004300u;
      bp.y = ((p0.z >> sh) & 15u) | (((p0.w >> sh) & 15u) << 16) | 0x43004300u;
      bp.z = ((p1.x >> sh) & 15u) | (((p1.y >> sh) & 15u) << 16) | 0x43004300u;
      bp.w = ((p1.z >> sh) & 15u) | (((p1.w >> sh) & 15u) << 16) | 0x43004300u;
      acc = __builtin_amdgcn_mfma_f32_32x32x16_bf16(
                a, __builtin_bit_cast(short8, bp), acc, 0, 0, 0);
    }
    #pragma unroll
    for (int r = 0; r < 16; ++r) accT[r] = fmaf(s, acc[r], accT[r]);
    __syncthreads();                        // all waves done reading T(c)
    if (c + 1 < NCH){
      #pragma unroll
      for (int j = 0; j < 4; ++j){
        T[(bcq*4 + j)*TSTRIDE + brow]      = bv[nx][0][j];
        T[(bcq*4 + j)*TSTRIDE + brow + 64] = bv[nx][1][j];
      }
    }
  }
  // C/D layout (HW-verified m74/m101): col=lane&31, row=(r&3)+8*(r>>2)+4*koct
  #pragma unroll
  for (int r = 0; r < 16; ++r){
    const int row = (r & 3) + 8*(r >> 2) + 4*koct;
    atomicAdd(out + (size_t)row*N_DIM + n, accT[r]);
  }
}

extern "C" void kernel_launch(void* const* d_in, const int* in_sizes, int n_in,
                              void* d_out, int out_size, void* d_ws, size_t ws_size,
                              hipStream_t stream)
{
  const float*  x      = (const float*)d_in[0];
  const uint32* qw     = (const uint32*)d_in[1];
  const uint32* qz     = (const uint32*)d_in[2];
  const float*  scales = (const float*)d_in[3];
  const float*  bias   = (const float*)d_in[4];
  const float*  theta  = (const float*)d_in[5];
  const int*    pairs  = (const int*)d_in[6];
  const float*  cs     = (const float*)d_in[7];
  float* out = (float*)d_out;

  rotate_kernel<<<dim3((M_DIM*64)/4), dim3(256), 0, stream>>>(x, theta, pairs, cs);
  init2_kernel<<<dim3(N_DIM/256), dim3(256), 0, stream>>>(qz, scales, bias, out);
  gemm_kernel<<<dim3((N_DIM/BN)*KSPLIT), dim3(512), 0, stream>>>(qw, scales, out);
}